// Round 1
// baseline (13396.860 us; speedup 1.0000x reference)
//
#include <hip/hip_runtime.h>

// ---------------------------------------------------------------------------
// PrimitiveDecoder: 4-layer LSTM (NH=1024), T=101 steps, tiny head.
// Strategy: persistent kernel, 256 blocks x 512 threads (1 block/CU -> all
// co-resident, custom device-scope barrier). bf16 fused weights [Whh|Wih]
// streamed from L3 with register prefetch of the next stage across the
// barrier spin. fp32 state/accumulation.
// ---------------------------------------------------------------------------

#define NHD   1024
#define TT    101
#define NBLK  256
#define NTH   512

// d_ws layout (bytes)
#define W2_OFF   0                       // 4*4096*2048 bf16 = 64 MiB
#define BIAS_OFF 67108864                // 16384 fp32
#define HBUF_OFF (BIAS_OFF + 65536)      // 2*4*1024 fp32 (time-parity h)
#define CNT_OFF  (HBUF_OFF + 32768)      // 404 barrier counters
#define WS_NEED  (CNT_OFF + 2048)

// output layout (fp32 flat): states[101][64], probs[101][2], samples[101]
#define OUT_PROBS 6464
#define OUT_SAMP  6666

// ---------------------------------------------------------------------------
// Weight fuse + bf16 convert: W2[l*4096+r][0:1024]=Whh, [1024:2048]=Wih (RNE)
// bias[l*4096+r] = bih + bhh
// ---------------------------------------------------------------------------
__global__ void convert_kernel(const float* __restrict__ Wih, const float* __restrict__ Whh,
                               const float* __restrict__ bih, const float* __restrict__ bhh,
                               unsigned short* __restrict__ W2, float* __restrict__ bias)
{
    const int row = blockIdx.x;                 // l*4096 + r, 16384 rows
    const float* hh = Whh + (size_t)row * 1024;
    const float* ih = Wih + (size_t)row * 1024;
    unsigned short* dst = W2 + (size_t)row * 2048;
    for (int k = threadIdx.x; k < 1024; k += blockDim.x) {
        unsigned a = __float_as_uint(hh[k]);
        unsigned b = __float_as_uint(ih[k]);
        dst[k]        = (unsigned short)((a + 0x7fffu + ((a >> 16) & 1u)) >> 16);
        dst[1024 + k] = (unsigned short)((b + 0x7fffu + ((b >> 16) & 1u)) >> 16);
    }
    if (threadIdx.x == 0) bias[row] = bih[row] + bhh[row];
}

// ---------------------------------------------------------------------------
// Main persistent LSTM kernel.
// Block b owns units b*4 .. b*4+3. Wave w: unit-local ul=w>>1, half=w&1.
// Each wave computes half of the 2048-dot for its unit's 4 gate rows.
// ---------------------------------------------------------------------------
__global__ __launch_bounds__(NTH, 1) void lstm_kernel(
    const float* __restrict__ z,
    const float* __restrict__ Wsm, const float* __restrict__ bs,
    const float* __restrict__ Wp,  const float* __restrict__ bp,
    const unsigned short* __restrict__ W2, const float* __restrict__ bias,
    float* __restrict__ hbuf, unsigned int* __restrict__ cnt,
    float* __restrict__ out)
{
    const int tid  = threadIdx.x;
    const int wv   = tid >> 6;
    const int lane = tid & 63;
    const int b    = blockIdx.x;
    const int ul   = wv >> 1;            // unit-local 0..3
    const int half = wv & 1;             // which half of the dot
    const int unit = (b << 2) + ul;      // 0..1023

    __shared__ float v[2048];            // [h_l(t-1) ; input]
    __shared__ float partial[4][4][2];   // [unit][gate][half]

    float cst0 = 0.f, cst1 = 0.f, cst2 = 0.f, cst3 = 0.f;  // cell state

    const uint4* __restrict__ W2v = (const uint4*)W2;

    uint4 cur[8], nxt[8];                // [gate*2 + chunk], 8 bf16 each
    #pragma unroll
    for (int i = 0; i < 8; ++i) { cur[i] = make_uint4(0,0,0,0); nxt[i] = make_uint4(0,0,0,0); }

    // initial weights: stage (t=0, l=0), full 2048-dot
    #pragma unroll
    for (int g = 0; g < 4; ++g) {
        const int base = ((unit + (g << 10)) << 8) + lane;
        cur[g*2+0] = W2v[base + ((half << 1) + 0) * 64];
        cur[g*2+1] = W2v[base + ((half << 1) + 1) * 64];
    }

    // initial v_low for stage 0: h0(-1) = 0
    v[tid] = 0.f;
    v[tid + 512] = 0.f;

    #pragma unroll 1
    for (int t = 0; t < TT; ++t) {
        const int par  = t & 1;          // parity of h written this step
        const int parp = par ^ 1;        // parity of h from previous step
        #pragma unroll
        for (int l = 0; l < 4; ++l) {
            const int s = (t << 2) + l;          // stage index / barrier id
            const bool full = (l > 0) || (t == 0);  // 2048-dot vs 1024 (l0,t>0)

            // ---- prefetch next stage's weights (independent of barriers) ----
            if (l < 3) {
                #pragma unroll
                for (int g = 0; g < 4; ++g) {
                    const int base = ((((l + 1) << 12) + unit + (g << 10)) << 8) + lane;
                    nxt[g*2+0] = W2v[base + ((half << 1) + 0) * 64];
                    nxt[g*2+1] = W2v[base + ((half << 1) + 1) * 64];
                }
            } else if (t < TT - 1) {
                // next stage is (t+1, 0): half-dot, Whh part only
                #pragma unroll
                for (int g = 0; g < 4; ++g) {
                    const int base = ((unit + (g << 10)) << 8) + lane;
                    nxt[g*2+0] = W2v[base + half * 64];
                }
            }

            // ---- stage v_high = layer input (only when full dot) ----
            if (full) {
                if (l > 0) {
                    const float* hin = hbuf + par * 4096 + ((l - 1) << 10);
                    v[1024 + tid]       = __hip_atomic_load(hin + tid,       __ATOMIC_RELAXED, __HIP_MEMORY_SCOPE_AGENT);
                    v[1024 + tid + 512] = __hip_atomic_load(hin + tid + 512, __ATOMIC_RELAXED, __HIP_MEMORY_SCOPE_AGENT);
                } else {  // l==0, t==0: input is z
                    v[1024 + tid]       = z[tid];
                    v[1024 + tid + 512] = z[tid + 512];
                }
            }
            __syncthreads();

            // ---- v fragments for this wave's half-dot ----
            const int nch = full ? 2 : 1;
            float4 vA0, vA1, vB0, vB1;
            {
                const int eb0 = (half * nch) * 512 + lane * 8;
                vA0 = *(const float4*)&v[eb0];
                vA1 = *(const float4*)&v[eb0 + 4];
            }
            if (full) {
                const int eb1 = (half * 2 + 1) * 512 + lane * 8;
                vB0 = *(const float4*)&v[eb1];
                vB1 = *(const float4*)&v[eb1 + 4];
            }

            // ---- 4 gate half-dots + wave reduction ----
            float acc[4];
            #pragma unroll
            for (int g = 0; g < 4; ++g) {
                const uint4 Wa = cur[g*2+0];
                float a;
                a = __uint_as_float(Wa.x << 16) * vA0.x;
                a = fmaf(__uint_as_float(Wa.x & 0xffff0000u), vA0.y, a);
                a = fmaf(__uint_as_float(Wa.y << 16),         vA0.z, a);
                a = fmaf(__uint_as_float(Wa.y & 0xffff0000u), vA0.w, a);
                a = fmaf(__uint_as_float(Wa.z << 16),         vA1.x, a);
                a = fmaf(__uint_as_float(Wa.z & 0xffff0000u), vA1.y, a);
                a = fmaf(__uint_as_float(Wa.w << 16),         vA1.z, a);
                a = fmaf(__uint_as_float(Wa.w & 0xffff0000u), vA1.w, a);
                if (full) {
                    const uint4 Wb = cur[g*2+1];
                    a = fmaf(__uint_as_float(Wb.x << 16),         vB0.x, a);
                    a = fmaf(__uint_as_float(Wb.x & 0xffff0000u), vB0.y, a);
                    a = fmaf(__uint_as_float(Wb.y << 16),         vB0.z, a);
                    a = fmaf(__uint_as_float(Wb.y & 0xffff0000u), vB0.w, a);
                    a = fmaf(__uint_as_float(Wb.z << 16),         vB1.x, a);
                    a = fmaf(__uint_as_float(Wb.z & 0xffff0000u), vB1.y, a);
                    a = fmaf(__uint_as_float(Wb.w << 16),         vB1.z, a);
                    a = fmaf(__uint_as_float(Wb.w & 0xffff0000u), vB1.w, a);
                }
                #pragma unroll
                for (int off = 32; off > 0; off >>= 1) a += __shfl_xor(a, off);
                acc[g] = a;
            }
            if (lane == 0) {
                partial[ul][0][half] = acc[0];
                partial[ul][1][half] = acc[1];
                partial[ul][2][half] = acc[2];
                partial[ul][3][half] = acc[3];
            }
            __syncthreads();

            // ---- gate nonlinearities + cell/h update (even-half waves) ----
            if (half == 0) {
                const float gi = acc[0] + partial[ul][0][1] + bias[(l << 12) + unit];
                const float gf = acc[1] + partial[ul][1][1] + bias[(l << 12) + unit + 1024];
                const float gg = acc[2] + partial[ul][2][1] + bias[(l << 12) + unit + 2048];
                const float go = acc[3] + partial[ul][3][1] + bias[(l << 12) + unit + 3072];
                const float si = 1.f / (1.f + expf(-gi));
                const float sf = 1.f / (1.f + expf(-gf));
                const float so = 1.f / (1.f + expf(-go));
                float cold = (l == 0) ? cst0 : ((l == 1) ? cst1 : ((l == 2) ? cst2 : cst3));
                const float cn = fmaf(sf, cold, si * tanhf(gg));
                if (l == 0) cst0 = cn; else if (l == 1) cst1 = cn; else if (l == 2) cst2 = cn; else cst3 = cn;
                const float hv = so * tanhf(cn);
                if (lane == 0)
                    __hip_atomic_store(hbuf + par * 4096 + (l << 10) + unit, hv,
                                       __ATOMIC_RELEASE, __HIP_MEMORY_SCOPE_AGENT);
            }

            // ---- pre-stage v_low for NEXT stage (its h_l(t-1) is already final) ----
            if (l < 3) {
                const float* hn = hbuf + parp * 4096 + ((l + 1) << 10);
                v[tid]       = __hip_atomic_load(hn + tid,       __ATOMIC_RELAXED, __HIP_MEMORY_SCOPE_AGENT);
                v[tid + 512] = __hip_atomic_load(hn + tid + 512, __ATOMIC_RELAXED, __HIP_MEMORY_SCOPE_AGENT);
            } else if (t < TT - 1) {
                const float* hn = hbuf + par * 4096;   // h0(t) for stage (t+1,0)
                v[tid]       = __hip_atomic_load(hn + tid,       __ATOMIC_RELAXED, __HIP_MEMORY_SCOPE_AGENT);
                v[tid + 512] = __hip_atomic_load(hn + tid + 512, __ATOMIC_RELAXED, __HIP_MEMORY_SCOPE_AGENT);
            }

            // ---- device-wide barrier for this stage ----
            __syncthreads();   // drains all waves' h stores (vmcnt) + LDS writes
            if (tid == 0) {
                __hip_atomic_fetch_add(&cnt[s], 1u, __ATOMIC_ACQ_REL, __HIP_MEMORY_SCOPE_AGENT);
                while (__hip_atomic_load(&cnt[s], __ATOMIC_ACQUIRE, __HIP_MEMORY_SCOPE_AGENT) < NBLK)
                    __builtin_amdgcn_s_sleep(4);
            }
            __syncthreads();

            // ---- rotate prefetched weights in (loads had the whole stage + spin) ----
            #pragma unroll
            for (int i = 0; i < 8; ++i) cur[i] = nxt[i];

            // ---- head: after layer-3 barrier, o = h3(t) is global-visible ----
            if (l == 3) {
                const float* o = hbuf + par * 4096 + 3072;
                if (b < 64 && wv == 0) {          // states row b
                    float a = 0.f;
                    #pragma unroll
                    for (int c4 = 0; c4 < 4; ++c4) {
                        const int k = c4 * 256 + lane * 4;
                        const float4 wr = *(const float4*)(Wsm + (b << 10) + k);
                        const float o0 = __hip_atomic_load(o + k + 0, __ATOMIC_RELAXED, __HIP_MEMORY_SCOPE_AGENT);
                        const float o1 = __hip_atomic_load(o + k + 1, __ATOMIC_RELAXED, __HIP_MEMORY_SCOPE_AGENT);
                        const float o2 = __hip_atomic_load(o + k + 2, __ATOMIC_RELAXED, __HIP_MEMORY_SCOPE_AGENT);
                        const float o3 = __hip_atomic_load(o + k + 3, __ATOMIC_RELAXED, __HIP_MEMORY_SCOPE_AGENT);
                        a = fmaf(wr.x, o0, a);
                        a = fmaf(wr.y, o1, a);
                        a = fmaf(wr.z, o2, a);
                        a = fmaf(wr.w, o3, a);
                    }
                    #pragma unroll
                    for (int off = 32; off > 0; off >>= 1) a += __shfl_xor(a, off);
                    if (lane == 0) out[t * 64 + b] = a + bs[b];
                } else if (b == 64 && wv == 0) {  // probs + sample
                    float a0 = 0.f, a1 = 0.f;
                    #pragma unroll
                    for (int c = 0; c < 16; ++c) {
                        const int k = c * 64 + lane;
                        const float ov = __hip_atomic_load(o + k, __ATOMIC_RELAXED, __HIP_MEMORY_SCOPE_AGENT);
                        a0 = fmaf(Wp[k],        ov, a0);
                        a1 = fmaf(Wp[1024 + k], ov, a1);
                    }
                    #pragma unroll
                    for (int off = 32; off > 0; off >>= 1) { a0 += __shfl_xor(a0, off); a1 += __shfl_xor(a1, off); }
                    if (lane == 0) {
                        const float l0 = a0 + bp[0] + 1.0f;   // P_BIAS on logit 0
                        const float l1 = a1 + bp[1];
                        float p0, p1;
                        if (t == TT - 1) { p0 = 0.f; p1 = 1.f; }
                        else {
                            const float m  = fmaxf(l0, l1);
                            const float e0 = expf(l0 - m), e1 = expf(l1 - m);
                            const float inv = 1.f / (e0 + e1);
                            p0 = e0 * inv; p1 = e1 * inv;
                        }
                        out[OUT_PROBS + t * 2 + 0] = p0;
                        out[OUT_PROBS + t * 2 + 1] = p1;
                        out[OUT_SAMP + t] = (t == TT - 1) ? 1.0f : 0.0f;
                    }
                }
            }
        }
    }
}

// ---------------------------------------------------------------------------
extern "C" void kernel_launch(void* const* d_in, const int* in_sizes, int n_in,
                              void* d_out, int out_size, void* d_ws, size_t ws_size,
                              hipStream_t stream)
{
    const float* z   = (const float*)d_in[0];
    const float* Wih = (const float*)d_in[1];
    const float* Whh = (const float*)d_in[2];
    const float* bih = (const float*)d_in[3];
    const float* bhh = (const float*)d_in[4];
    const float* Ws  = (const float*)d_in[5];
    const float* bs  = (const float*)d_in[6];
    const float* Wp  = (const float*)d_in[7];
    const float* bp  = (const float*)d_in[8];
    float* out = (float*)d_out;

    char* ws = (char*)d_ws;
    unsigned short* W2 = (unsigned short*)(ws + W2_OFF);
    float* bias        = (float*)(ws + BIAS_OFF);
    float* hbuf        = (float*)(ws + HBUF_OFF);
    unsigned int* cnt  = (unsigned int*)(ws + CNT_OFF);

    // zero h double-buffer + barrier counters (ws is poisoned before each call)
    hipMemsetAsync(ws + HBUF_OFF, 0, 32768 + 2048, stream);

    convert_kernel<<<16384, 256, 0, stream>>>(Wih, Whh, bih, bhh, W2, bias);
    lstm_kernel<<<NBLK, NTH, 0, stream>>>(z, Ws, bs, Wp, bp, W2, bias, hbuf, cnt, out);
}

// Round 2
// 1175.756 us; speedup vs baseline: 11.3943x; 11.3943x over previous
//
#include <hip/hip_runtime.h>

// ---------------------------------------------------------------------------
// PrimitiveDecoder: 4-layer LSTM (NH=1024), T=101 steps, tiny head.
//
// Round-2 design: layer-specialized pipelined persistent kernel.
//  - 4 groups x 64 blocks (grid 256 = 1 block/CU), 512 threads.
//  - Group l computes layer l for all t; cross-stage sync via single-writer
//    epoch flags (flag[l][gb] = steps completed) -- NO atomic RMW, relaxed
//    polling + acquire fence. Critical path ~104 handoffs, not 404 global
//    barriers (round-1 barrier cost was ~30 us each).
//  - Full-history h buffer hbuf[l][t][1024] fp32 (1.65 MB): single-writer,
//    write-once => no ring back-pressure, no overwrite hazards.
//  - Weights register-resident f16: each lane holds 8 rows x 32 cols
//    (128 VGPRs), loaded once directly from fp32 inputs (no convert pass).
//    Compute: v_dot2_f32_f16 (f32 accumulate).
//  - Head (Ws/Wp/softmax/sample) on group 1, waves 1-2, lag t-3 (overlaps
//    wave 0's next-step polling); 3-step drain after the main loop.
// ---------------------------------------------------------------------------

#define TT    101
#define NBLK  256
#define NTH   512

// ws layout (bytes)
#define HBUF_BYTES (4 * TT * 1024 * 4)      // 1,654,784
#define FLAGS_OFF  HBUF_BYTES               // 4*64 uint = 1 KB

// output layout (fp32 flat): states[101][64], probs[101][2], samples[101]
#define OUT_PROBS 6464
#define OUT_SAMP  6666

typedef _Float16 h2 __attribute__((ext_vector_type(2)));

__device__ __forceinline__ h2 mkh2(float a, float b) {
    h2 r; r.x = (_Float16)a; r.y = (_Float16)b; return r;
}

#if __has_builtin(__builtin_amdgcn_fdot2)
__device__ __forceinline__ float fdot2(h2 a, h2 b, float c) {
    return __builtin_amdgcn_fdot2(a, b, c, false);
}
#else
__device__ __forceinline__ float fdot2(h2 a, h2 b, float c) {
    return fmaf((float)a.x, (float)b.x, fmaf((float)a.y, (float)b.y, c));
}
#endif

__device__ __forceinline__ float agload(const float* p) {
    return __hip_atomic_load(p, __ATOMIC_RELAXED, __HIP_MEMORY_SCOPE_AGENT);
}
__device__ __forceinline__ unsigned agloadu(const unsigned* p) {
    return __hip_atomic_load(p, __ATOMIC_RELAXED, __HIP_MEMORY_SCOPE_AGENT);
}

// wait until all 64 flags of group 3 reach `need` (wave-wide; lane i polls flag i)
__device__ __forceinline__ void wait_g3(const unsigned* flags, int lane, unsigned need) {
    const unsigned* f3 = flags + 192 + lane;
    while (__ballot(agloadu(f3) >= need) != ~0ull)
        __builtin_amdgcn_s_sleep(2);
    __builtin_amdgcn_fence(__ATOMIC_ACQUIRE, "agent");
}

__device__ __forceinline__ void head_states(int th, int gb, int lane,
        const float* hbuf, const unsigned* flags,
        const float* Ws, const float* bs, float* out) {
    wait_g3(flags, lane, (unsigned)(th + 1));
    const float* h3 = hbuf + ((3 * TT + th) << 10) + (lane << 4);
    const float* wr = Ws + (gb << 10) + (lane << 4);
    float a = 0.f;
    #pragma unroll
    for (int k = 0; k < 16; ++k) a = fmaf(wr[k], agload(h3 + k), a);
    #pragma unroll
    for (int off = 1; off < 64; off <<= 1) a += __shfl_xor(a, off);
    if (lane == 0) out[th * 64 + gb] = a + bs[gb];
}

__device__ __forceinline__ void head_probs(int th, int lane,
        const float* hbuf, const unsigned* flags,
        const float* Wp, const float* bp, float* out) {
    wait_g3(flags, lane, (unsigned)(th + 1));
    const float* h3 = hbuf + ((3 * TT + th) << 10) + (lane << 4);
    float a0 = 0.f, a1 = 0.f;
    #pragma unroll
    for (int k = 0; k < 16; ++k) {
        const float hv = agload(h3 + k);
        a0 = fmaf(Wp[(lane << 4) + k],        hv, a0);
        a1 = fmaf(Wp[1024 + (lane << 4) + k], hv, a1);
    }
    #pragma unroll
    for (int off = 1; off < 64; off <<= 1) { a0 += __shfl_xor(a0, off); a1 += __shfl_xor(a1, off); }
    if (lane == 0) {
        float p0, p1;
        if (th == TT - 1) { p0 = 0.f; p1 = 1.f; }
        else {
            const float l0 = a0 + bp[0] + 1.0f;   // P_BIAS on logit 0
            const float l1 = a1 + bp[1];
            const float m  = fmaxf(l0, l1);
            const float e0 = expf(l0 - m), e1 = expf(l1 - m);
            const float inv = 1.f / (e0 + e1);
            p0 = e0 * inv; p1 = e1 * inv;
        }
        out[OUT_PROBS + 2 * th]     = p0;
        out[OUT_PROBS + 2 * th + 1] = p1;
        out[OUT_SAMP + th] = (th == TT - 1) ? 1.0f : 0.0f;
    }
}

// ---------------------------------------------------------------------------
__global__ __launch_bounds__(NTH, 2) void lstm_kernel(
    const float* __restrict__ z,
    const float* __restrict__ Wih, const float* __restrict__ Whh,
    const float* __restrict__ bih, const float* __restrict__ bhh,
    const float* __restrict__ Ws,  const float* __restrict__ bs,
    const float* __restrict__ Wp,  const float* __restrict__ bp,
    float* __restrict__ hbuf, unsigned* __restrict__ flags,
    float* __restrict__ out)
{
    const int tid  = threadIdx.x;
    const int wv   = tid >> 6;
    const int lane = tid & 63;
    const int l    = blockIdx.x >> 6;     // group == layer
    const int gb   = blockIdx.x & 63;     // block-in-group
    const int uA   = (gb << 4) + (wv << 1);   // first unit of this wave
    const int uB   = uA + 1;

    __shared__ h2 vh[1024];   // 2048 f16 cols: [h_l(t-1) (1024) | h_{l-1}(t) (1024)]

    // ---- load this wave's weight slice into registers (fp32 -> f16) ----
    // lane c covers cols [c*16, c*16+16) of each 1024-half.
    // rows r: r<4 -> unit uA gate r; r>=4 -> unit uB gate r-4. Gate order i,f,g,o.
    h2 w[8][16];
    #pragma unroll
    for (int r = 0; r < 8; ++r) {
        const int u = (r < 4) ? uA : uB;
        const int g = r & 3;
        const size_t rowoff = ((size_t)((l << 12) + (g << 10) + u) << 10) + (lane << 4);
        const float4* rh = (const float4*)(Whh + rowoff);
        const float4* ri = (const float4*)(Wih + rowoff);
        #pragma unroll
        for (int j = 0; j < 4; ++j) {
            const float4 f = rh[j];
            w[r][2*j+0] = mkh2(f.x, f.y);
            w[r][2*j+1] = mkh2(f.z, f.w);
        }
        #pragma unroll
        for (int j = 0; j < 4; ++j) {
            const float4 f = ri[j];
            w[r][8+2*j+0] = mkh2(f.x, f.y);
            w[r][8+2*j+1] = mkh2(f.z, f.w);
        }
    }

    // ---- combined biases for this wave's two units ----
    float bA[4], bB[4];
    #pragma unroll
    for (int g = 0; g < 4; ++g) {
        const int iA = (l << 12) + (g << 10) + uA;
        bA[g] = bih[iA] + bhh[iA];
        bB[g] = bih[iA + 1] + bhh[iA + 1];
    }

    float cst = 0.f;   // cell state: lane0 -> uA, lane1 -> uB (others unused)

    #pragma unroll 1
    for (int t = 0; t < TT; ++t) {
        const bool full = (l > 0) || (t == 0);   // layer-0 input is zero for t>0

        // ---- wave 0: wait for dependencies (single-writer epoch flags) ----
        if (wv == 0) {
            const bool ns = (t > 0);   // own group done step t-1
            const bool np = (l > 0);   // prev group done step t
            if (ns || np) {
                const unsigned* fs = flags + (l << 6) + lane;
                const unsigned* fp = flags + (((l > 0) ? (l - 1) : 0) << 6) + lane;
                const unsigned needs = (unsigned)t, needp = (unsigned)(t + 1);
                for (;;) {
                    bool ok = true;
                    if (ns) ok = ok && (agloadu(fs) >= needs);
                    if (np) ok = ok && (agloadu(fp) >= needp);
                    if (__ballot(ok) == ~0ull) break;
                    __builtin_amdgcn_s_sleep(2);
                }
                __builtin_amdgcn_fence(__ATOMIC_ACQUIRE, "agent");
            }
        }
        __syncthreads();

        // ---- stage v into LDS as f16 ----
        if (tid < 256) {                      // part1: h_l(t-1)
            const int col = tid << 2;
            float x0 = 0.f, x1 = 0.f, x2 = 0.f, x3 = 0.f;
            if (t > 0) {
                const float* p = hbuf + ((l * TT + (t - 1)) << 10) + col;
                x0 = agload(p); x1 = agload(p + 1); x2 = agload(p + 2); x3 = agload(p + 3);
            }
            vh[(tid << 1)]     = mkh2(x0, x1);
            vh[(tid << 1) + 1] = mkh2(x2, x3);
        } else {                              // part2: h_{l-1}(t) (or z at l0/t0)
            const int c2 = (tid - 256) << 2;
            if (l > 0) {
                const float* p = hbuf + (((l - 1) * TT + t) << 10) + c2;
                vh[512 + ((tid - 256) << 1)]     = mkh2(agload(p),     agload(p + 1));
                vh[512 + ((tid - 256) << 1) + 1] = mkh2(agload(p + 2), agload(p + 3));
            } else if (t == 0) {
                vh[512 + ((tid - 256) << 1)]     = mkh2(z[c2],     z[c2 + 1]);
                vh[512 + ((tid - 256) << 1) + 1] = mkh2(z[c2 + 2], z[c2 + 3]);
            }
            // l==0 && t>0: part2 unused (skipped in compute)
        }
        __syncthreads();

        // ---- 8 gate-row half-dots per wave (dot2 f16 -> f32) ----
        float acc[8] = {0.f,0.f,0.f,0.f,0.f,0.f,0.f,0.f};
        {
            const h2* vp = vh + (lane << 3);
            #pragma unroll
            for (int k = 0; k < 8; ++k) {
                const h2 v2 = vp[k];
                #pragma unroll
                for (int r = 0; r < 8; ++r) acc[r] = fdot2(w[r][k], v2, acc[r]);
            }
            if (full) {
                const h2* vq = vh + 512 + (lane << 3);
                #pragma unroll
                for (int k = 0; k < 8; ++k) {
                    const h2 v2 = vq[k];
                    #pragma unroll
                    for (int r = 0; r < 8; ++r) acc[r] = fdot2(w[r][8 + k], v2, acc[r]);
                }
            }
        }
        #pragma unroll
        for (int off = 1; off < 64; off <<= 1) {
            #pragma unroll
            for (int r = 0; r < 8; ++r) acc[r] += __shfl_xor(acc[r], off);
        }

        // ---- gate nonlinearities + state update (lanes 0,1 per wave) ----
        if (lane < 2) {
            float s0, s1, s2, s3;
            if (lane == 0) { s0 = acc[0]+bA[0]; s1 = acc[1]+bA[1]; s2 = acc[2]+bA[2]; s3 = acc[3]+bA[3]; }
            else           { s0 = acc[4]+bB[0]; s1 = acc[5]+bB[1]; s2 = acc[6]+bB[2]; s3 = acc[7]+bB[3]; }
            const float si = 1.f / (1.f + expf(-s0));
            const float sf = 1.f / (1.f + expf(-s1));
            const float so = 1.f / (1.f + expf(-s3));
            cst = fmaf(sf, cst, si * tanhf(s2));
            const float hv = so * tanhf(cst);
            __hip_atomic_store(hbuf + ((l * TT + t) << 10) + uA + lane, hv,
                               __ATOMIC_RELAXED, __HIP_MEMORY_SCOPE_AGENT);
        }
        __syncthreads();   // all waves' h stores drained (vmcnt) before flag

        // ---- publish epoch flag (single writer, release) ----
        if (tid == 0)
            __hip_atomic_store(flags + (l << 6) + gb, (unsigned)(t + 1),
                               __ATOMIC_RELEASE, __HIP_MEMORY_SCOPE_AGENT);

        // ---- head on group 1, waves 1-2, lag t-3 (overlaps next poll) ----
        if (l == 1 && t >= 3) {
            if (wv == 1)                 head_states(t - 3, gb, lane, hbuf, flags, Ws, bs, out);
            else if (wv == 2 && gb == 0) head_probs(t - 3, lane, hbuf, flags, Wp, bp, out);
        }
    }

    // ---- head drain: th = 98, 99, 100 ----
    if (l == 1) {
        for (int th = TT - 3; th < TT; ++th) {
            if (wv == 1)                 head_states(th, gb, lane, hbuf, flags, Ws, bs, out);
            else if (wv == 2 && gb == 0) head_probs(th, lane, hbuf, flags, Wp, bp, out);
        }
    }
}

// ---------------------------------------------------------------------------
extern "C" void kernel_launch(void* const* d_in, const int* in_sizes, int n_in,
                              void* d_out, int out_size, void* d_ws, size_t ws_size,
                              hipStream_t stream)
{
    const float* z   = (const float*)d_in[0];
    const float* Wih = (const float*)d_in[1];
    const float* Whh = (const float*)d_in[2];
    const float* bih = (const float*)d_in[3];
    const float* bhh = (const float*)d_in[4];
    const float* Ws  = (const float*)d_in[5];
    const float* bs  = (const float*)d_in[6];
    const float* Wp  = (const float*)d_in[7];
    const float* bp  = (const float*)d_in[8];
    float* out = (float*)d_out;

    float*    hbuf  = (float*)d_ws;
    unsigned* flags = (unsigned*)((char*)d_ws + FLAGS_OFF);

    hipMemsetAsync(flags, 0, 1024, stream);   // epoch flags start at 0
    lstm_kernel<<<NBLK, NTH, 0, stream>>>(z, Wih, Whh, bih, bhh, Ws, bs, Wp, bp,
                                          hbuf, flags, out);
}

// Round 3
// 771.723 us; speedup vs baseline: 17.3597x; 1.5235x over previous
//
#include <hip/hip_runtime.h>

// ---------------------------------------------------------------------------
// PrimitiveDecoder: 4-layer LSTM (NH=1024), T=101 steps, tiny head.
//
// Round-3 design: layer-specialized pipeline (4 groups x 64 blocks, 512 thr,
// grid 256 = 1 block/CU) with FENCELESS cross-block sync:
//  - ALL cross-block traffic (h vectors, epoch flags) uses SYSTEM-scope
//    relaxed atomics -> sc0 sc1, coherent at the memory-side Infinity Cache.
//    No acquire/release fences anywhere => no buffer_inv / buffer_wbl2
//    (round-2's ~10us/step cost: 256 L2-invalidate + 256 L2-writeback ops
//    per step, serializing per-XCD).
//  - Producer ordering: h stores are write-through; s_waitcnt vmcnt(0) +
//    __syncthreads before the single flag store => h is at the coherence
//    point before the flag becomes visible. Consumer issues data loads only
//    after observing the flag; loads bypass caches => no stale reads.
//  - Weights register-resident f16 (128 VGPR/lane), v_dot2_f32_f16 compute.
//  - Head (Ws/Wp/softmax/sample) on group 0 (waves 1-2) at lag 4: the
//    g0->g1->g2->g3->g0(t+4) cycle needs period >= (3*handoff+head)/4,
//    which is below the base step period -> head rides free. Grid stays 256.
// ---------------------------------------------------------------------------

#define TT    101
#define NBLK  256
#define NTH   512

// ws layout (bytes)
#define HBUF_BYTES (4 * TT * 1024 * 4)      // 1,654,784
#define FLAGS_OFF  HBUF_BYTES               // 4*64 uint = 1 KB

// output layout (fp32 flat): states[101][64], probs[101][2], samples[101]
#define OUT_PROBS 6464
#define OUT_SAMP  6666

typedef _Float16 h2 __attribute__((ext_vector_type(2)));

__device__ __forceinline__ h2 mkh2(float a, float b) {
    h2 r; r.x = (_Float16)a; r.y = (_Float16)b; return r;
}

#if __has_builtin(__builtin_amdgcn_fdot2)
__device__ __forceinline__ float fdot2(h2 a, h2 b, float c) {
    return __builtin_amdgcn_fdot2(a, b, c, false);
}
#else
__device__ __forceinline__ float fdot2(h2 a, h2 b, float c) {
    return fmaf((float)a.x, (float)b.x, fmaf((float)a.y, (float)b.y, c));
}
#endif

// SYSTEM-scope relaxed atomics: sc0 sc1 (bypass L1/L2, IF$-coherent), no fences.
__device__ __forceinline__ float sysload(const float* p) {
    return __hip_atomic_load(p, __ATOMIC_RELAXED, __HIP_MEMORY_SCOPE_SYSTEM);
}
__device__ __forceinline__ unsigned sysloadu(const unsigned* p) {
    return __hip_atomic_load(p, __ATOMIC_RELAXED, __HIP_MEMORY_SCOPE_SYSTEM);
}
__device__ __forceinline__ void sysstore(float* p, float v) {
    __hip_atomic_store(p, v, __ATOMIC_RELAXED, __HIP_MEMORY_SCOPE_SYSTEM);
}
__device__ __forceinline__ void sysstoreu(unsigned* p, unsigned v) {
    __hip_atomic_store(p, v, __ATOMIC_RELAXED, __HIP_MEMORY_SCOPE_SYSTEM);
}

// wave-wide wait: lane i polls group-3 flag i until all >= need
__device__ __forceinline__ void wait_g3(const unsigned* flags, int lane, unsigned need) {
    const unsigned* f3 = flags + 192 + lane;
    while (__ballot(sysloadu(f3) >= need) != ~0ull)
        __builtin_amdgcn_s_sleep(2);
    __atomic_signal_fence(__ATOMIC_ACQUIRE);   // compiler-only; HW order via issue dep
}

__device__ __forceinline__ void head_states(int th, int gb, int lane,
        const float* hbuf, const unsigned* flags,
        const float* __restrict__ Ws, const float* __restrict__ bs, float* out) {
    wait_g3(flags, lane, (unsigned)(th + 1));
    const float* h3 = hbuf + ((3 * TT + th) << 10) + (lane << 4);
    const float* wr = Ws + (gb << 10) + (lane << 4);   // normal cached loads (L1 stays warm now)
    float a = 0.f;
    #pragma unroll
    for (int k = 0; k < 16; ++k) a = fmaf(wr[k], sysload(h3 + k), a);
    #pragma unroll
    for (int off = 1; off < 64; off <<= 1) a += __shfl_xor(a, off);
    if (lane == 0) out[th * 64 + gb] = a + bs[gb];
}

__device__ __forceinline__ void head_probs(int th, int lane,
        const float* hbuf, const unsigned* flags,
        const float* __restrict__ Wp, const float* __restrict__ bp, float* out) {
    wait_g3(flags, lane, (unsigned)(th + 1));
    const float* h3 = hbuf + ((3 * TT + th) << 10) + (lane << 4);
    float a0 = 0.f, a1 = 0.f;
    #pragma unroll
    for (int k = 0; k < 16; ++k) {
        const float hv = sysload(h3 + k);
        a0 = fmaf(Wp[(lane << 4) + k],        hv, a0);
        a1 = fmaf(Wp[1024 + (lane << 4) + k], hv, a1);
    }
    #pragma unroll
    for (int off = 1; off < 64; off <<= 1) { a0 += __shfl_xor(a0, off); a1 += __shfl_xor(a1, off); }
    if (lane == 0) {
        float p0, p1;
        if (th == TT - 1) { p0 = 0.f; p1 = 1.f; }
        else {
            const float l0 = a0 + bp[0] + 1.0f;   // P_BIAS on logit 0
            const float l1 = a1 + bp[1];
            const float m  = fmaxf(l0, l1);
            const float e0 = expf(l0 - m), e1 = expf(l1 - m);
            const float inv = 1.f / (e0 + e1);
            p0 = e0 * inv; p1 = e1 * inv;
        }
        out[OUT_PROBS + 2 * th]     = p0;
        out[OUT_PROBS + 2 * th + 1] = p1;
        out[OUT_SAMP + th] = (th == TT - 1) ? 1.0f : 0.0f;
    }
}

// ---------------------------------------------------------------------------
__global__ __launch_bounds__(NTH, 2) void lstm_kernel(
    const float* __restrict__ z,
    const float* __restrict__ Wih, const float* __restrict__ Whh,
    const float* __restrict__ bih, const float* __restrict__ bhh,
    const float* __restrict__ Ws,  const float* __restrict__ bs,
    const float* __restrict__ Wp,  const float* __restrict__ bp,
    float* __restrict__ hbuf, unsigned* __restrict__ flags,
    float* __restrict__ out)
{
    const int tid  = threadIdx.x;
    const int wv   = tid >> 6;
    const int lane = tid & 63;
    const int l    = blockIdx.x >> 6;     // group == layer
    const int gb   = blockIdx.x & 63;     // block-in-group
    const int uA   = (gb << 4) + (wv << 1);   // first unit of this wave
    const int uB   = uA + 1;

    __shared__ h2 vh[1024];   // 2048 f16 cols: [h_l(t-1) | h_{l-1}(t)]

    // ---- weight slice into registers (fp32 -> f16), 128 VGPRs/lane ----
    h2 w[8][16];
    #pragma unroll
    for (int r = 0; r < 8; ++r) {
        const int u = (r < 4) ? uA : uB;
        const int g = r & 3;
        const size_t rowoff = ((size_t)((l << 12) + (g << 10) + u) << 10) + (lane << 4);
        const float4* rh = (const float4*)(Whh + rowoff);
        const float4* ri = (const float4*)(Wih + rowoff);
        #pragma unroll
        for (int j = 0; j < 4; ++j) {
            const float4 f = rh[j];
            w[r][2*j+0] = mkh2(f.x, f.y);
            w[r][2*j+1] = mkh2(f.z, f.w);
        }
        #pragma unroll
        for (int j = 0; j < 4; ++j) {
            const float4 f = ri[j];
            w[r][8+2*j+0] = mkh2(f.x, f.y);
            w[r][8+2*j+1] = mkh2(f.z, f.w);
        }
    }

    float bA[4], bB[4];
    #pragma unroll
    for (int g = 0; g < 4; ++g) {
        const int iA = (l << 12) + (g << 10) + uA;
        bA[g] = bih[iA] + bhh[iA];
        bB[g] = bih[iA + 1] + bhh[iA + 1];
    }

    float cst = 0.f;   // cell state: lane0 -> uA, lane1 -> uB

    #pragma unroll 1
    for (int t = 0; t < TT; ++t) {
        const bool full = (l > 0) || (t == 0);

        // ---- wave 0: poll dependency flags (fenceless, system-scope) ----
        if (wv == 0) {
            const bool ns = (t > 0);
            const bool np = (l > 0);
            if (ns || np) {
                const unsigned* fs = flags + (l << 6) + lane;
                const unsigned* fp = flags + (((l > 0) ? (l - 1) : 0) << 6) + lane;
                const unsigned needs = (unsigned)t, needp = (unsigned)(t + 1);
                for (;;) {
                    bool ok = true;
                    if (ns) ok = ok && (sysloadu(fs) >= needs);
                    if (np) ok = ok && (sysloadu(fp) >= needp);
                    if (__ballot(ok) == ~0ull) break;
                    __builtin_amdgcn_s_sleep(2);
                }
                __atomic_signal_fence(__ATOMIC_ACQUIRE);
            }
        }
        __syncthreads();

        // ---- stage v into LDS as f16 (system-scope loads of h) ----
        if (tid < 256) {                      // part1: h_l(t-1)
            const int col = tid << 2;
            float x0 = 0.f, x1 = 0.f, x2 = 0.f, x3 = 0.f;
            if (t > 0) {
                const float* p = hbuf + ((l * TT + (t - 1)) << 10) + col;
                x0 = sysload(p); x1 = sysload(p + 1); x2 = sysload(p + 2); x3 = sysload(p + 3);
            }
            vh[(tid << 1)]     = mkh2(x0, x1);
            vh[(tid << 1) + 1] = mkh2(x2, x3);
        } else {                              // part2: h_{l-1}(t) (or z at l0/t0)
            const int c2 = (tid - 256) << 2;
            if (l > 0) {
                const float* p = hbuf + (((l - 1) * TT + t) << 10) + c2;
                vh[512 + ((tid - 256) << 1)]     = mkh2(sysload(p),     sysload(p + 1));
                vh[512 + ((tid - 256) << 1) + 1] = mkh2(sysload(p + 2), sysload(p + 3));
            } else if (t == 0) {
                vh[512 + ((tid - 256) << 1)]     = mkh2(z[c2],     z[c2 + 1]);
                vh[512 + ((tid - 256) << 1) + 1] = mkh2(z[c2 + 2], z[c2 + 3]);
            }
        }
        __syncthreads();

        // ---- 8 gate-row half-dots (dot2 f16 -> f32) ----
        float acc[8] = {0.f,0.f,0.f,0.f,0.f,0.f,0.f,0.f};
        {
            const h2* vp = vh + (lane << 3);
            #pragma unroll
            for (int k = 0; k < 8; ++k) {
                const h2 v2 = vp[k];
                #pragma unroll
                for (int r = 0; r < 8; ++r) acc[r] = fdot2(w[r][k], v2, acc[r]);
            }
            if (full) {
                const h2* vq = vh + 512 + (lane << 3);
                #pragma unroll
                for (int k = 0; k < 8; ++k) {
                    const h2 v2 = vq[k];
                    #pragma unroll
                    for (int r = 0; r < 8; ++r) acc[r] = fdot2(w[r][8 + k], v2, acc[r]);
                }
            }
        }
        #pragma unroll
        for (int off = 1; off < 64; off <<= 1) {
            #pragma unroll
            for (int r = 0; r < 8; ++r) acc[r] += __shfl_xor(acc[r], off);
        }

        // ---- gate nonlinearities + state update (lanes 0,1 per wave) ----
        if (lane < 2) {
            float s0, s1, s2, s3;
            if (lane == 0) { s0 = acc[0]+bA[0]; s1 = acc[1]+bA[1]; s2 = acc[2]+bA[2]; s3 = acc[3]+bA[3]; }
            else           { s0 = acc[4]+bB[0]; s1 = acc[5]+bB[1]; s2 = acc[6]+bB[2]; s3 = acc[7]+bB[3]; }
            const float si = 1.f / (1.f + expf(-s0));
            const float sf = 1.f / (1.f + expf(-s1));
            const float so = 1.f / (1.f + expf(-s3));
            cst = fmaf(sf, cst, si * tanhf(s2));
            const float hv = so * tanhf(cst);
            sysstore(hbuf + ((l * TT + t) << 10) + uA + lane, hv);   // write-through
        }

        // ---- order: h stores reach IF$ before flag store ----
        __atomic_signal_fence(__ATOMIC_SEQ_CST);
        __builtin_amdgcn_s_waitcnt(0);            // drain this wave's stores
        __syncthreads();                          // all waves drained
        if (tid == 0)
            sysstoreu(flags + (l << 6) + gb, (unsigned)(t + 1));

        // ---- head on group 0, waves 1-2, lag 4 (off the critical cycle) ----
        if (l == 0 && t >= 4) {
            if (wv == 1)                 head_states(t - 4, gb, lane, hbuf, flags, Ws, bs, out);
            else if (wv == 2 && gb == 0) head_probs(t - 4, lane, hbuf, flags, Wp, bp, out);
        }
    }

    // ---- head drain: th = 97..100 ----
    if (l == 0) {
        for (int th = TT - 4; th < TT; ++th) {
            if (wv == 1)                 head_states(th, gb, lane, hbuf, flags, Ws, bs, out);
            else if (wv == 2 && gb == 0) head_probs(th, lane, hbuf, flags, Wp, bp, out);
        }
    }
}

// ---------------------------------------------------------------------------
extern "C" void kernel_launch(void* const* d_in, const int* in_sizes, int n_in,
                              void* d_out, int out_size, void* d_ws, size_t ws_size,
                              hipStream_t stream)
{
    const float* z   = (const float*)d_in[0];
    const float* Wih = (const float*)d_in[1];
    const float* Whh = (const float*)d_in[2];
    const float* bih = (const float*)d_in[3];
    const float* bhh = (const float*)d_in[4];
    const float* Ws  = (const float*)d_in[5];
    const float* bs  = (const float*)d_in[6];
    const float* Wp  = (const float*)d_in[7];
    const float* bp  = (const float*)d_in[8];
    float* out = (float*)d_out;

    float*    hbuf  = (float*)d_ws;
    unsigned* flags = (unsigned*)((char*)d_ws + FLAGS_OFF);

    hipMemsetAsync(flags, 0, 1024, stream);   // epoch flags start at 0
    lstm_kernel<<<NBLK, NTH, 0, stream>>>(z, Wih, Whh, bih, bhh, Ws, bs, Wp, bp,
                                          hbuf, flags, out);
}

// Round 4
// 566.139 us; speedup vs baseline: 23.6636x; 1.3631x over previous
//
#include <hip/hip_runtime.h>

// ---------------------------------------------------------------------------
// PrimitiveDecoder: 4-layer LSTM (NH=1024), T=101 steps, tiny head.
//
// Round-4 design: layer-specialized pipeline with VALUE-CARRYING sync.
//  - 4 groups x 64 blocks (512 thr) = 256 main blocks + 65 head blocks.
//  - h stored packed f16 (2 KB/step) with 8 REPLICAS; producers store each
//    packed dword to all replicas (parallel stores). Consumers poll their
//    replica (gb&7) with 16B cache-bypass loads (sc0 sc1) until the NaN
//    sentinel (0xFFFFFFFF, memset 0xFF) disappears -> the poll IS the
//    staging load. No flags, no fences, no store-drain on critical path.
//    (Round-3's 6.6us/step = 512K scalar dword transactions serialized on
//    32 IF$ lines; now ~16K x 16B transactions spread over 8 replicas.)
//  - LDS dot layout stride-64 (vh[k*64+lane]) -> conflict-free (round 3:
//    16-way conflicts, 3.2e6 SQ_LDS_BANK_CONFLICT).
//  - Weights register-resident f16 (128 VGPR/lane), v_dot2_f32_f16.
//  - Head: 65 dedicated blocks (1 wave each), self-paced polling layer-3
//    slabs -> zero impact on the LSTM recurrence period.
// ---------------------------------------------------------------------------

#define TT    101
#define NBLK  256
#define NHEAD 65
#define NTH   512
#define NREP  8
#define SLAB_U32 512                               // 1024 f16 per slab replica

#define HB16_BYTES (4 * TT * NREP * SLAB_U32 * 4)  // 6,615,040 B

// output layout (fp32 flat): states[101][64], probs[101][2], samples[101]
#define OUT_PROBS 6464
#define OUT_SAMP  6666

typedef _Float16 h2 __attribute__((ext_vector_type(2)));

__device__ __forceinline__ h2 mkh2(float a, float b) {
    h2 r; r.x = (_Float16)a; r.y = (_Float16)b; return r;
}

#if __has_builtin(__builtin_amdgcn_fdot2)
__device__ __forceinline__ float fdot2(h2 a, h2 b, float c) {
    return __builtin_amdgcn_fdot2(a, b, c, false);
}
#else
__device__ __forceinline__ float fdot2(h2 a, h2 b, float c) {
    return fmaf((float)a.x, (float)b.x, fmaf((float)a.y, (float)b.y, c));
}
#endif

// 16B cache-bypass load (coherent at IF$): waitcnt inside the asm so the
// result regs are valid on exit regardless of compiler scheduling.
__device__ __forceinline__ uint4 load16_bypass(const uint4* p) {
    uint4 r;
    asm volatile("global_load_dwordx4 %0, %1, off sc0 sc1\n\ts_waitcnt vmcnt(0)"
                 : "=v"(r) : "v"(p) : "memory");
    return r;
}
__device__ __forceinline__ void store4_bypass(unsigned* p, unsigned v) {
    asm volatile("global_store_dword %0, %1, off sc0 sc1" :: "v"(p), "v"(v) : "memory");
}

// poll until no dword equals the 0xFFFFFFFF sentinel (f16 NaN pair; |h|<1
// so real data can never be the sentinel)
__device__ __forceinline__ uint4 poll16(const uint4* p) {
    uint4 r = load16_bypass(p);
    while (r.x == 0xFFFFFFFFu || r.y == 0xFFFFFFFFu ||
           r.z == 0xFFFFFFFFu || r.w == 0xFFFFFFFFu) {
        __builtin_amdgcn_s_sleep(1);
        r = load16_bypass(p);
    }
    return r;
}

__device__ __forceinline__ float2 unpack(unsigned u) {
    h2 p = __builtin_bit_cast(h2, u);
    return make_float2((float)p.x, (float)p.y);
}

// ---------------------------------------------------------------------------
__global__ __launch_bounds__(NTH, 2) void lstm_kernel(
    const float* __restrict__ z,
    const float* __restrict__ Wih, const float* __restrict__ Whh,
    const float* __restrict__ bih, const float* __restrict__ bhh,
    const float* __restrict__ Ws,  const float* __restrict__ bs,
    const float* __restrict__ Wp,  const float* __restrict__ bp,
    unsigned* __restrict__ hb16, float* __restrict__ out)
{
    const int tid  = threadIdx.x;
    const int wv   = tid >> 6;
    const int lane = tid & 63;

    // ================= head blocks (self-paced, poll layer-3 slabs) ========
    if (blockIdx.x >= NBLK) {
        if (wv != 0) return;                       // 1 wave per head block
        const int hb  = blockIdx.x - NBLK;         // 0..63 states, 64 probs
        const int rep = hb & (NREP - 1);
        if (hb < 64) {
            float wr[16];
            #pragma unroll
            for (int k = 0; k < 16; ++k) wr[k] = Ws[(hb << 10) + (lane << 4) + k];
            const float bsv = bs[hb];
            for (int th = 0; th < TT; ++th) {
                const uint4* slab = (const uint4*)(hb16 + (size_t)((3 * TT + th) * NREP + rep) * SLAB_U32);
                const uint4 r0 = poll16(slab + 2 * lane);
                const uint4 r1 = poll16(slab + 2 * lane + 1);
                const unsigned u8[8] = {r0.x, r0.y, r0.z, r0.w, r1.x, r1.y, r1.z, r1.w};
                float a = 0.f;
                #pragma unroll
                for (int j = 0; j < 8; ++j) {
                    const float2 p = unpack(u8[j]);
                    a = fmaf(wr[2 * j], p.x, a);
                    a = fmaf(wr[2 * j + 1], p.y, a);
                }
                #pragma unroll
                for (int off = 1; off < 64; off <<= 1) a += __shfl_xor(a, off);
                if (lane == 0) out[th * 64 + hb] = a + bsv;
            }
        } else {
            float w0[16], w1[16];
            #pragma unroll
            for (int k = 0; k < 16; ++k) {
                w0[k] = Wp[(lane << 4) + k];
                w1[k] = Wp[1024 + (lane << 4) + k];
            }
            const float bp0 = bp[0], bp1 = bp[1];
            for (int th = 0; th < TT; ++th) {
                const uint4* slab = (const uint4*)(hb16 + (size_t)((3 * TT + th) * NREP + rep) * SLAB_U32);
                const uint4 r0 = poll16(slab + 2 * lane);
                const uint4 r1 = poll16(slab + 2 * lane + 1);
                const unsigned u8[8] = {r0.x, r0.y, r0.z, r0.w, r1.x, r1.y, r1.z, r1.w};
                float a0 = 0.f, a1 = 0.f;
                #pragma unroll
                for (int j = 0; j < 8; ++j) {
                    const float2 p = unpack(u8[j]);
                    a0 = fmaf(w0[2 * j], p.x, a0); a0 = fmaf(w0[2 * j + 1], p.y, a0);
                    a1 = fmaf(w1[2 * j], p.x, a1); a1 = fmaf(w1[2 * j + 1], p.y, a1);
                }
                #pragma unroll
                for (int off = 1; off < 64; off <<= 1) { a0 += __shfl_xor(a0, off); a1 += __shfl_xor(a1, off); }
                if (lane == 0) {
                    float p0, p1;
                    if (th == TT - 1) { p0 = 0.f; p1 = 1.f; }
                    else {
                        const float l0 = a0 + bp0 + 1.0f;   // P_BIAS on logit 0
                        const float l1 = a1 + bp1;
                        const float m  = fmaxf(l0, l1);
                        const float e0 = expf(l0 - m), e1 = expf(l1 - m);
                        const float inv = 1.f / (e0 + e1);
                        p0 = e0 * inv; p1 = e1 * inv;
                    }
                    out[OUT_PROBS + 2 * th]     = p0;
                    out[OUT_PROBS + 2 * th + 1] = p1;
                    out[OUT_SAMP + th] = (th == TT - 1) ? 1.0f : 0.0f;
                }
            }
        }
        return;
    }

    // ================= main LSTM blocks ====================================
    const int l   = blockIdx.x >> 6;          // layer
    const int gb  = blockIdx.x & 63;          // block-in-group
    const int uA  = (gb << 4) + (wv << 1);    // this wave's first unit
    const int rep = gb & (NREP - 1);

    __shared__ __align__(16) h2 vh[1024];     // [h_l(t-1) (512 pairs) | input (512 pairs)]

    // ---- weight slice into registers (fp32 -> f16), stride-64 column map ----
    // lane c covers column-pairs {c, c+64, ..., c+448} of each 1024-half.
    h2 w[8][16];
    #pragma unroll
    for (int r = 0; r < 8; ++r) {
        const int u = (r < 4) ? uA : (uA + 1);
        const int g = r & 3;
        const size_t row = ((size_t)((l << 12) + (g << 10) + u)) << 10;
        #pragma unroll
        for (int k = 0; k < 8; ++k) {
            const float2 fh = *(const float2*)(Whh + row + (size_t)(((k << 6) + lane) << 1));
            w[r][k] = mkh2(fh.x, fh.y);
            const float2 fi = *(const float2*)(Wih + row + (size_t)(((k << 6) + lane) << 1));
            w[r][8 + k] = mkh2(fi.x, fi.y);
        }
    }

    float bA[4], bB[4];
    #pragma unroll
    for (int g = 0; g < 4; ++g) {
        const int iA = (l << 12) + (g << 10) + uA;
        bA[g] = bih[iA] + bhh[iA];
        bB[g] = bih[iA + 1] + bhh[iA + 1];
    }

    float cst = 0.f;   // cell state: lane0 -> uA, lane1 -> uA+1

    #pragma unroll 1
    for (int t = 0; t < TT; ++t) {
        const bool full = (l > 0) || (t == 0);

        // ---- staging: poll-load h into LDS (the poll IS the sync) ----
        if (tid < 128) {                      // part1: h_l(t-1)
            if (t == 0) {
                *(uint4*)&vh[tid << 2] = make_uint4(0, 0, 0, 0);
            } else {
                const uint4* slab = (const uint4*)(hb16 + (size_t)((l * TT + (t - 1)) * NREP + rep) * SLAB_U32);
                *(uint4*)&vh[tid << 2] = poll16(slab + tid);
            }
        } else if (tid < 256) {               // part2: h_{l-1}(t) or z
            const int j = tid - 128;
            if (l > 0) {
                const uint4* slab = (const uint4*)(hb16 + (size_t)(((l - 1) * TT + t) * NREP + rep) * SLAB_U32);
                *(uint4*)&vh[512 + (j << 2)] = poll16(slab + j);
            } else if (t == 0) {
                const float4 f0 = *(const float4*)(z + (j << 3));
                const float4 f1 = *(const float4*)(z + (j << 3) + 4);
                h2 tmp[4] = {mkh2(f0.x, f0.y), mkh2(f0.z, f0.w),
                             mkh2(f1.x, f1.y), mkh2(f1.z, f1.w)};
                *(uint4*)&vh[512 + (j << 2)] = *(uint4*)tmp;
            }
        }
        __syncthreads();

        // ---- 8 gate-row dots, conflict-free LDS (stride-64) ----
        float acc[8] = {0.f, 0.f, 0.f, 0.f, 0.f, 0.f, 0.f, 0.f};
        #pragma unroll
        for (int k = 0; k < 8; ++k) {
            const h2 v2 = vh[(k << 6) + lane];
            #pragma unroll
            for (int r = 0; r < 8; ++r) acc[r] = fdot2(w[r][k], v2, acc[r]);
        }
        if (full) {
            #pragma unroll
            for (int k = 0; k < 8; ++k) {
                const h2 v2 = vh[512 + (k << 6) + lane];
                #pragma unroll
                for (int r = 0; r < 8; ++r) acc[r] = fdot2(w[r][8 + k], v2, acc[r]);
            }
        }
        #pragma unroll
        for (int off = 1; off < 64; off <<= 1) {
            #pragma unroll
            for (int r = 0; r < 8; ++r) acc[r] += __shfl_xor(acc[r], off);
        }

        // ---- gate nonlinearities (lanes 0,1), pack, publish to 8 replicas ----
        float hv = 0.f;
        if (lane < 2) {
            float s0, s1, s2, s3;
            if (lane == 0) { s0 = acc[0] + bA[0]; s1 = acc[1] + bA[1]; s2 = acc[2] + bA[2]; s3 = acc[3] + bA[3]; }
            else           { s0 = acc[4] + bB[0]; s1 = acc[5] + bB[1]; s2 = acc[6] + bB[2]; s3 = acc[7] + bB[3]; }
            const float si = 1.f / (1.f + expf(-s0));
            const float sf = 1.f / (1.f + expf(-s1));
            const float so = 1.f / (1.f + expf(-s3));
            cst = fmaf(sf, cst, si * tanhf(s2));
            hv  = so * tanhf(cst);
        }
        const float hB = __shfl(hv, 1);
        if (lane == 0) {
            const unsigned packed = __builtin_bit_cast(unsigned, mkh2(hv, hB));
            unsigned* base = hb16 + (size_t)(l * TT + t) * NREP * SLAB_U32 + (gb << 3) + wv;
            #pragma unroll
            for (int r = 0; r < NREP; ++r) store4_bypass(base + r * SLAB_U32, packed);
        }
        __syncthreads();   // protect vh against next iteration's staging writes
    }
}

// ---------------------------------------------------------------------------
extern "C" void kernel_launch(void* const* d_in, const int* in_sizes, int n_in,
                              void* d_out, int out_size, void* d_ws, size_t ws_size,
                              hipStream_t stream)
{
    const float* z   = (const float*)d_in[0];
    const float* Wih = (const float*)d_in[1];
    const float* Whh = (const float*)d_in[2];
    const float* bih = (const float*)d_in[3];
    const float* bhh = (const float*)d_in[4];
    const float* Ws  = (const float*)d_in[5];
    const float* bs  = (const float*)d_in[6];
    const float* Wp  = (const float*)d_in[7];
    const float* bp  = (const float*)d_in[8];
    float* out = (float*)d_out;

    unsigned* hb16 = (unsigned*)d_ws;

    // sentinel-init the h replicas (f16 NaN pattern; ws is 0xAA-poisoned
    // before every timed call, so this must run every call)
    hipMemsetAsync(hb16, 0xFF, HB16_BYTES, stream);
    lstm_kernel<<<NBLK + NHEAD, NTH, 0, stream>>>(z, Wih, Whh, bih, bhh,
                                                  Ws, bs, Wp, bp, hb16, out);
}

// Round 5
// 512.442 us; speedup vs baseline: 26.1432x; 1.1048x over previous
//
#include <hip/hip_runtime.h>

// ---------------------------------------------------------------------------
// PrimitiveDecoder: 4-layer LSTM (NH=1024), T=101 steps, tiny head.
//
// Round-5: layer-pipelined persistent kernel (4 groups x 64 blocks, 512 thr,
// grid 256 = 1 block/CU), value-carrying sync (NaN-sentinel poll on packed
// f16 h replicas), restructured so NO store-ack is on the critical path:
//  - waves 0-3: poll-stage h chunks into LDS (they never global-store, so
//    their poll's vmcnt(0) waits only on their own loads)
//  - waves 0-7: dot (4x ds_read_b128, chunk-aligned weight layout) +
//    DPP-based wave reduction (VALU pipe; round-4 used 48 ds_swizzle/wave
//    ~1us/step of LDS-pipe serialization) + uniform nonlinearity from
//    readlane SGPRs
//  - wave 7: publishes the block's 8 packed dwords x 8 replicas as ONE
//    64-lane scatter store after barrier2; its ack drains at next barrier1,
//    overlapped with the staging waves' detect spin (round 4 serialized
//    ~1-2us of system-scope store-ack into every step)
//  - wave 6 (group 0 blocks + group1/gb0): head at lag 3, non-blocking
//    in-loop tries + blocking drain after the loop. Grid exactly 256.
// ---------------------------------------------------------------------------

#define TT    101
#define NBLK  256
#define NTH   512
#define NREP  8
#define SLAB_U32 512                               // 1024 f16 per replica
#define HB16_BYTES (4 * TT * NREP * SLAB_U32 * 4)  // 6,615,040 B
#define OUT_PROBS 6464
#define OUT_SAMP  6666
#define SENT 0xFFFFFFFFu

typedef _Float16 h2 __attribute__((ext_vector_type(2)));

__device__ __forceinline__ h2 mkh2(float a, float b) {
    h2 r; r.x = (_Float16)a; r.y = (_Float16)b; return r;
}
__device__ __forceinline__ unsigned pack2(float a, float b) {
    return __builtin_bit_cast(unsigned, mkh2(a, b));
}
__device__ __forceinline__ h2 as_h2(unsigned u) { return __builtin_bit_cast(h2, u); }

#if __has_builtin(__builtin_amdgcn_fdot2)
__device__ __forceinline__ float fdot2(h2 a, h2 b, float c) {
    return __builtin_amdgcn_fdot2(a, b, c, false);
}
#else
__device__ __forceinline__ float fdot2(h2 a, h2 b, float c) {
    return fmaf((float)a.x, (float)b.x, fmaf((float)a.y, (float)b.y, c));
}
#endif

// 16B cache-bypass load (IF$-coherent); waitcnt inside so result regs valid.
__device__ __forceinline__ uint4 load16_bypass(const uint4* p) {
    uint4 r;
    asm volatile("global_load_dwordx4 %0, %1, off sc0 sc1\n\ts_waitcnt vmcnt(0)"
                 : "=v"(r) : "v"(p) : "memory");
    return r;
}
__device__ __forceinline__ void store4_bypass(unsigned* p, unsigned v) {
    asm volatile("global_store_dword %0, %1, off sc0 sc1" :: "v"(p), "v"(v) : "memory");
}
__device__ __forceinline__ uint4 poll16(const uint4* p) {
    uint4 r = load16_bypass(p);
    while (r.x == SENT || r.y == SENT || r.z == SENT || r.w == SENT) {
        __builtin_amdgcn_s_sleep(1);
        r = load16_bypass(p);
    }
    return r;
}

// rocPRIM-style full-wave (64) sum via DPP; total broadcast via readlane(63).
__device__ __forceinline__ float wave_sum(float x) {
    int v;
    v = __builtin_amdgcn_update_dpp(0, __builtin_bit_cast(int, x), 0x111, 0xf, 0xf, false);
    x += __builtin_bit_cast(float, v);                                  // row_shr:1
    v = __builtin_amdgcn_update_dpp(0, __builtin_bit_cast(int, x), 0x112, 0xf, 0xf, false);
    x += __builtin_bit_cast(float, v);                                  // row_shr:2
    v = __builtin_amdgcn_update_dpp(0, __builtin_bit_cast(int, x), 0x114, 0xf, 0xe, false);
    x += __builtin_bit_cast(float, v);                                  // row_shr:4
    v = __builtin_amdgcn_update_dpp(0, __builtin_bit_cast(int, x), 0x118, 0xf, 0xc, false);
    x += __builtin_bit_cast(float, v);                                  // row_shr:8
    v = __builtin_amdgcn_update_dpp(0, __builtin_bit_cast(int, x), 0x142, 0xa, 0xf, false);
    x += __builtin_bit_cast(float, v);                                  // row_bcast:15
    v = __builtin_amdgcn_update_dpp(0, __builtin_bit_cast(int, x), 0x143, 0xc, 0xf, false);
    x += __builtin_bit_cast(float, v);                                  // row_bcast:31
    return __builtin_bit_cast(float, __builtin_amdgcn_readlane(__builtin_bit_cast(int, x), 63));
}

__device__ __forceinline__ float sigm(float x) { return 1.f / (1.f + expf(-x)); }

// ---------------------------------------------------------------------------
__global__ __launch_bounds__(NTH, 2) void lstm_kernel(
    const float* __restrict__ z,
    const float* __restrict__ Wih, const float* __restrict__ Whh,
    const float* __restrict__ bih, const float* __restrict__ bhh,
    const float* __restrict__ Ws,  const float* __restrict__ bs,
    const float* __restrict__ Wp,  const float* __restrict__ bp,
    unsigned* __restrict__ hb16, float* __restrict__ out)
{
    const int tid  = threadIdx.x;
    const int wv   = tid >> 6;
    const int lane = tid & 63;
    const int l    = blockIdx.x >> 6;          // layer / group
    const int gb   = blockIdx.x & 63;          // block-in-group
    const int uA   = (gb << 4) + (wv << 1);    // wave's first unit

    __shared__ __align__(16) uint4 vh4[256];   // 256 chunks: [part1 128 | part2 128]
    __shared__ unsigned hout[8];               // packed h pair per wave

    // ---- weights -> registers (fp32 -> f16), chunk-aligned layout --------
    // lane's dot coverage: chunks {lane, 64+lane} of each part
    //   k0-3:  Whh cols 8*lane   .. +7      k4-7:  Whh cols 512+8*lane .. +7
    //   k8-11: Wih cols 8*lane   .. +7      k12-15:Wih cols 512+8*lane .. +7
    h2 w[8][16];
    #pragma unroll
    for (int r = 0; r < 8; ++r) {
        const int u = uA + (r >> 2);
        const int g = r & 3;
        const size_t row = ((size_t)((l << 12) + (g << 10) + u)) << 10;
        const float4* pa = (const float4*)(Whh + row + (lane << 3));
        const float4* pb = (const float4*)(Whh + row + 512 + (lane << 3));
        const float4* pc = (const float4*)(Wih + row + (lane << 3));
        const float4* pd = (const float4*)(Wih + row + 512 + (lane << 3));
        float4 f;
        f = pa[0]; w[r][0]  = mkh2(f.x, f.y); w[r][1]  = mkh2(f.z, f.w);
        f = pa[1]; w[r][2]  = mkh2(f.x, f.y); w[r][3]  = mkh2(f.z, f.w);
        f = pb[0]; w[r][4]  = mkh2(f.x, f.y); w[r][5]  = mkh2(f.z, f.w);
        f = pb[1]; w[r][6]  = mkh2(f.x, f.y); w[r][7]  = mkh2(f.z, f.w);
        f = pc[0]; w[r][8]  = mkh2(f.x, f.y); w[r][9]  = mkh2(f.z, f.w);
        f = pc[1]; w[r][10] = mkh2(f.x, f.y); w[r][11] = mkh2(f.z, f.w);
        f = pd[0]; w[r][12] = mkh2(f.x, f.y); w[r][13] = mkh2(f.z, f.w);
        f = pd[1]; w[r][14] = mkh2(f.x, f.y); w[r][15] = mkh2(f.z, f.w);
    }

    float bA[4], bB[4];
    #pragma unroll
    for (int g = 0; g < 4; ++g) {
        const int iA = (l << 12) + (g << 10) + uA;
        bA[g] = bih[iA] + bhh[iA];
        bB[g] = bih[iA + 1] + bhh[iA + 1];
    }

    // ---- head role (wave 6) ----------------------------------------------
    const bool role_states = (l == 0 && wv == 6);
    const bool role_probs  = (l == 1 && gb == 0 && wv == 6);
    float hw0[16], hw1[16], hb0 = 0.f, hb1 = 0.f;
    if (role_states) {
        #pragma unroll
        for (int k = 0; k < 16; ++k) hw0[k] = Ws[(gb << 10) + (lane << 4) + k];
        hb0 = bs[gb];
    } else if (role_probs) {
        #pragma unroll
        for (int k = 0; k < 16; ++k) {
            hw0[k] = Wp[(lane << 4) + k];
            hw1[k] = Wp[1024 + (lane << 4) + k];
        }
        hb0 = bp[0]; hb1 = bp[1];
    }
    int th = 0;

    float cstA = 0.f, cstB = 0.f;

    #pragma unroll 1
    for (int t = 0; t < TT; ++t) {
        const bool full = (l > 0) || (t == 0);
        const int rep = (gb + wv) & (NREP - 1);

        // ---- staging (waves 0-3; they never global-store) ----
        if (wv < 2) {                              // part1: h_l(t-1)
            const int c = (wv << 6) + lane;
            if (t == 0) vh4[c] = make_uint4(0, 0, 0, 0);
            else {
                const uint4* slab = (const uint4*)(hb16 + (size_t)((l * TT + t - 1) * NREP + rep) * SLAB_U32);
                vh4[c] = poll16(slab + c);
            }
        } else if (wv < 4) {                       // part2: h_{l-1}(t) or z
            const int c = ((wv - 2) << 6) + lane;
            if (l > 0) {
                const uint4* slab = (const uint4*)(hb16 + (size_t)(((l - 1) * TT + t) * NREP + rep) * SLAB_U32);
                vh4[128 + c] = poll16(slab + c);
            } else if (t == 0) {
                const float4 f0 = *(const float4*)(z + (c << 3));
                const float4 f1 = *(const float4*)(z + (c << 3) + 4);
                vh4[128 + c] = make_uint4(pack2(f0.x, f0.y), pack2(f0.z, f0.w),
                                          pack2(f1.x, f1.y), pack2(f1.z, f1.w));
            }
        }
        __syncthreads();                           // barrier1

        // ---- dot: 8 gate rows per wave, 4x ds_read_b128 ----
        float acc[8] = {0.f, 0.f, 0.f, 0.f, 0.f, 0.f, 0.f, 0.f};
        {
            const uint4 A1 = vh4[lane];
            const uint4 A2 = vh4[64 + lane];
            const unsigned a8[8] = {A1.x, A1.y, A1.z, A1.w, A2.x, A2.y, A2.z, A2.w};
            #pragma unroll
            for (int k = 0; k < 8; ++k) {
                const h2 v2 = as_h2(a8[k]);
                #pragma unroll
                for (int r = 0; r < 8; ++r) acc[r] = fdot2(w[r][k], v2, acc[r]);
            }
            if (full) {
                const uint4 B1 = vh4[128 + lane];
                const uint4 B2 = vh4[192 + lane];
                const unsigned b8[8] = {B1.x, B1.y, B1.z, B1.w, B2.x, B2.y, B2.z, B2.w};
                #pragma unroll
                for (int k = 0; k < 8; ++k) {
                    const h2 v2 = as_h2(b8[k]);
                    #pragma unroll
                    for (int r = 0; r < 8; ++r) acc[r] = fdot2(w[r][8 + k], v2, acc[r]);
                }
            }
        }

        // ---- DPP reduce (VALU pipe) -> uniform gate sums ----
        float tot[8];
        #pragma unroll
        for (int r = 0; r < 8; ++r) tot[r] = wave_sum(acc[r]);

        // ---- uniform nonlinearity on all lanes ----
        cstA = fmaf(sigm(tot[1] + bA[1]), cstA, sigm(tot[0] + bA[0]) * tanhf(tot[2] + bA[2]));
        cstB = fmaf(sigm(tot[5] + bB[1]), cstB, sigm(tot[4] + bB[0]) * tanhf(tot[6] + bB[2]));
        const float hA = sigm(tot[3] + bA[3]) * tanhf(cstA);
        const float hB = sigm(tot[7] + bB[3]) * tanhf(cstB);
        if (lane == 0) hout[wv] = pack2(hA, hB);
        __syncthreads();                           // barrier2

        if (wv == 7) {
            // ---- publish: ONE 64-lane scatter store (8 replicas x 8 dwords).
            // Ack drains at next barrier1, overlapped with detect spin.
            const unsigned val = hout[lane & 7];
            unsigned* addr = hb16 + (size_t)(l * TT + t) * NREP * SLAB_U32
                           + (size_t)(lane >> 3) * SLAB_U32 + (gb << 3) + (lane & 7);
            store4_bypass(addr, val);
        } else if ((role_states || role_probs) && th < TT && th <= t - 3) {
            // ---- head: non-blocking single-shot try at lag 3 ----
            const int hrep = (gb + th) & (NREP - 1);
            const uint4* slab3 = (const uint4*)(hb16 + (size_t)((3 * TT + th) * NREP + hrep) * SLAB_U32);
            const uint4 r0 = load16_bypass(slab3 + (lane << 1));
            const uint4 r1 = load16_bypass(slab3 + (lane << 1) + 1);
            const bool ok = !(r0.x == SENT || r0.y == SENT || r0.z == SENT || r0.w == SENT ||
                              r1.x == SENT || r1.y == SENT || r1.z == SENT || r1.w == SENT);
            if (__ballot(ok) == ~0ull) {
                const unsigned u8[8] = {r0.x, r0.y, r0.z, r0.w, r1.x, r1.y, r1.z, r1.w};
                if (role_states) {
                    float a = 0.f;
                    #pragma unroll
                    for (int j = 0; j < 8; ++j) {
                        const h2 p = as_h2(u8[j]);
                        a = fmaf(hw0[2 * j], (float)p.x, a);
                        a = fmaf(hw0[2 * j + 1], (float)p.y, a);
                    }
                    const float tots = wave_sum(a);
                    if (lane == 0) out[th * 64 + gb] = tots + hb0;
                } else {
                    float a0 = 0.f, a1 = 0.f;
                    #pragma unroll
                    for (int j = 0; j < 8; ++j) {
                        const h2 p = as_h2(u8[j]);
                        a0 = fmaf(hw0[2 * j], (float)p.x, a0); a0 = fmaf(hw0[2 * j + 1], (float)p.y, a0);
                        a1 = fmaf(hw1[2 * j], (float)p.x, a1); a1 = fmaf(hw1[2 * j + 1], (float)p.y, a1);
                    }
                    const float t0 = wave_sum(a0), t1 = wave_sum(a1);
                    if (lane == 0) {
                        float p0, p1;
                        if (th == TT - 1) { p0 = 0.f; p1 = 1.f; }
                        else {
                            const float l0 = t0 + hb0 + 1.0f;   // P_BIAS
                            const float l1 = t1 + hb1;
                            const float m  = fmaxf(l0, l1);
                            const float e0 = expf(l0 - m), e1 = expf(l1 - m);
                            const float inv = 1.f / (e0 + e1);
                            p0 = e0 * inv; p1 = e1 * inv;
                        }
                        out[OUT_PROBS + 2 * th]     = p0;
                        out[OUT_PROBS + 2 * th + 1] = p1;
                        out[OUT_SAMP + th] = (th == TT - 1) ? 1.0f : 0.0f;
                    }
                }
                ++th;
            }
        }
    }

    // ---- head drain (blocking) ----
    if (role_states || role_probs) {
        while (th < TT) {
            const int hrep = (gb + th) & (NREP - 1);
            const uint4* slab3 = (const uint4*)(hb16 + (size_t)((3 * TT + th) * NREP + hrep) * SLAB_U32);
            const uint4 r0 = poll16(slab3 + (lane << 1));
            const uint4 r1 = poll16(slab3 + (lane << 1) + 1);
            const unsigned u8[8] = {r0.x, r0.y, r0.z, r0.w, r1.x, r1.y, r1.z, r1.w};
            if (role_states) {
                float a = 0.f;
                #pragma unroll
                for (int j = 0; j < 8; ++j) {
                    const h2 p = as_h2(u8[j]);
                    a = fmaf(hw0[2 * j], (float)p.x, a);
                    a = fmaf(hw0[2 * j + 1], (float)p.y, a);
                }
                const float tots = wave_sum(a);
                if (lane == 0) out[th * 64 + gb] = tots + hb0;
            } else {
                float a0 = 0.f, a1 = 0.f;
                #pragma unroll
                for (int j = 0; j < 8; ++j) {
                    const h2 p = as_h2(u8[j]);
                    a0 = fmaf(hw0[2 * j], (float)p.x, a0); a0 = fmaf(hw0[2 * j + 1], (float)p.y, a0);
                    a1 = fmaf(hw1[2 * j], (float)p.x, a1); a1 = fmaf(hw1[2 * j + 1], (float)p.y, a1);
                }
                const float t0 = wave_sum(a0), t1 = wave_sum(a1);
                if (lane == 0) {
                    float p0, p1;
                    if (th == TT - 1) { p0 = 0.f; p1 = 1.f; }
                    else {
                        const float l0 = t0 + hb0 + 1.0f;
                        const float l1 = t1 + hb1;
                        const float m  = fmaxf(l0, l1);
                        const float e0 = expf(l0 - m), e1 = expf(l1 - m);
                        const float inv = 1.f / (e0 + e1);
                        p0 = e0 * inv; p1 = e1 * inv;
                    }
                    out[OUT_PROBS + 2 * th]     = p0;
                    out[OUT_PROBS + 2 * th + 1] = p1;
                    out[OUT_SAMP + th] = (th == TT - 1) ? 1.0f : 0.0f;
                }
            }
            ++th;
        }
    }
}

// ---------------------------------------------------------------------------
extern "C" void kernel_launch(void* const* d_in, const int* in_sizes, int n_in,
                              void* d_out, int out_size, void* d_ws, size_t ws_size,
                              hipStream_t stream)
{
    const float* z   = (const float*)d_in[0];
    const float* Wih = (const float*)d_in[1];
    const float* Whh = (const float*)d_in[2];
    const float* bih = (const float*)d_in[3];
    const float* bhh = (const float*)d_in[4];
    const float* Ws  = (const float*)d_in[5];
    const float* bs  = (const float*)d_in[6];
    const float* Wp  = (const float*)d_in[7];
    const float* bp  = (const float*)d_in[8];
    float* out = (float*)d_out;

    unsigned* hb16 = (unsigned*)d_ws;

    // sentinel-init replicas (ws is re-poisoned before every timed call)
    hipMemsetAsync(hb16, 0xFF, HB16_BYTES, stream);
    lstm_kernel<<<NBLK, NTH, 0, stream>>>(z, Wih, Whh, bih, bhh,
                                          Ws, bs, Wp, bp, hb16, out);
}